// Round 8
// baseline (173.199 us; speedup 1.0000x reference)
//
#include <hip/hip_runtime.h>

// VolumeRenderer R18: length-sorted rays (counting sort) + R13 frame.
// Validated model (R12-R17): total = fill(46) + prep(max(cvt 23 HBM-bound,
// walk ~5 hidden)) + seg(30) + gaps(8). Seg's 30us >> its ~10us issue
// demand because lanes are 64 RANDOM rays: mean length ~65 steps but the
// wave runs until ALL lanes freeze => ~174 executed steps/slot (2.5x waste).
// R18 sorts rays by estimated step count S ~ (tmax-tmin)*128*sum|d| /
// (1+0.128*sum|d|) via u8 counting sort:
//   prep += 32 hist blocks (partial hists, no zero-init hazard; also
//          zeroes the scatter cursor -- nothing else touches it in prep);
//   scatter: tiny kernel, per-block redundant scan + atomic bin cursors
//          -> perm[sortedpos] = ray;
//   seg: wave takes 64 CONSECUTIVE SORTED rays via perm -> lanes freeze
//          together; late segs break at chunk 0.
// Per-ray arithmetic untouched (walk unpermuted, cp by ray id) => output
// bit-identical, absmax stays at the 1/256 quant floor.

constexpr int   R_DIM    = 128;
constexpr int   N_VOX    = R_DIM * R_DIM * R_DIM;
constexpr int   N_STEPS  = 192;
constexpr int   NSEG     = 4;
constexpr int   SEG_LEN  = N_STEPS / NSEG;   // 48
constexpr float STEP_SZ  = 0.001f;
constexpr float CUBE_SZ  = 1.0f / 128.0f;
constexpr int   PIPE     = 8;
constexpr float SIG_MAX  = 5.5f;
constexpr int   CVT_BLOCKS  = (N_VOX / 4 + 255) / 256;   // 2048
constexpr int   HIST_BLOCKS = 32;
constexpr int   NBIN        = 256;

__device__ __forceinline__ float sigmoid_fast(float x) {
    return __builtin_amdgcn_rcpf(1.0f + __expf(-x));
}

// One geometric DDA step -> cell coords + exact delta. Bit-identical to the
// reference walk. smin==0 exactly (f in [0,1] -> every per-axis lo <= 0).
__device__ __forceinline__ void geom_step(
    float tl, float tmax,
    float oxR, float oyR, float ozR, float dxR, float dyR, float dzR,
    float ix, float iy, float iz, float ipx, float ipy, float ipz,
    int& i0, int& i1, int& i2, float& d)
{
    float px = __fadd_rn(oxR, __fmul_rn(tl, dxR));
    float py = __fadd_rn(oyR, __fmul_rn(tl, dyR));
    float pz = __fadd_rn(ozR, __fmul_rn(tl, dzR));

    float c0 = fminf(fmaxf(floorf(px), 0.0f), 127.0f);
    float c1 = fminf(fmaxf(floorf(py), 0.0f), 127.0f);
    float c2 = fminf(fmaxf(floorf(pz), 0.0f), 127.0f);
    i0 = (int)c0;   // dead (DCE'd) in walk-only use
    i1 = (int)c1;
    i2 = (int)c2;

    float t1x = __fmul_rn(__fsub_rn(c0, px), ix);
    float t1y = __fmul_rn(__fsub_rn(c1, py), iy);
    float t1z = __fmul_rn(__fsub_rn(c2, pz), iz);
    float hix = __fadd_rn(t1x, ipx);
    float hiy = __fadd_rn(t1y, ipy);
    float hiz = __fadd_rn(t1z, ipz);
    float smax = fminf(fminf(fminf(hix, hiy), hiz), 1e9f);

    d = __fadd_rn(__fmul_rn(smax, CUBE_SZ), STEP_SZ);
    d = (tl < tmax) ? d : 0.0f;   // inactive -> exact no-op (t frozen)
}

__device__ __forceinline__ void ray_setup(
    const float* __restrict__ origins, const float* __restrict__ dirs, int i,
    float& oxR, float& oyR, float& ozR, float& dxR, float& dyR, float& dzR,
    float& ix, float& iy, float& iz,
    float& ipx, float& ipy, float& ipz,
    float& tmin, float& tmax)
{
    float ox = origins[3 * i + 0];
    float oy = origins[3 * i + 1];
    float oz = origins[3 * i + 2];
    float dx = dirs[3 * i + 0];
    float dy = dirs[3 * i + 1];
    float dz = dirs[3 * i + 2];

    float n2 = __fadd_rn(__fadd_rn(__fmul_rn(dx, dx), __fmul_rn(dy, dy)),
                         __fmul_rn(dz, dz));
    float nrm = sqrtf(n2);
    dx = dx / nrm;
    dy = dy / nrm;
    dz = dz / nrm;

    ix = 1.0f / __fadd_rn(dx, 1e-9f);
    iy = 1.0f / __fadd_rn(dy, 1e-9f);
    iz = 1.0f / __fadd_rn(dz, 1e-9f);

    ipx = fmaxf(ix, 0.0f);
    ipy = fmaxf(iy, 0.0f);
    ipz = fmaxf(iz, 0.0f);

    float t1x = __fmul_rn(-ox, ix), t2x = __fadd_rn(t1x, ix);
    float t1y = __fmul_rn(-oy, iy), t2y = __fadd_rn(t1y, iy);
    float t1z = __fmul_rn(-oz, iz), t2z = __fadd_rn(t1z, iz);
    float lox = fminf(t1x, t2x), hix = fmaxf(t1x, t2x);
    float loy = fminf(t1y, t2y), hiy = fmaxf(t1y, t2y);
    float loz = fminf(t1z, t2z), hiz = fmaxf(t1z, t2z);
    tmin = fmaxf(fmaxf(fmaxf(lox, loy), loz), 0.0f);
    tmax = fminf(fminf(fminf(hix, hiy), hiz), 1e9f);

    // exact *2^7 (scaling lemma keeps the walk bit-identical)
    oxR = __fmul_rn(ox, 128.0f);
    oyR = __fmul_rn(oy, 128.0f);
    ozR = __fmul_rn(oz, 128.0f);
    dxR = __fmul_rn(dx, 128.0f);
    dyR = __fmul_rn(dy, 128.0f);
    dzR = __fmul_rn(dz, 128.0f);
}

__device__ __forceinline__ unsigned pack_voxel(float4 v) {
    unsigned ur = (unsigned)__float2int_rn(sigmoid_fast(v.x) * 255.0f);
    unsigned ug = (unsigned)__float2int_rn(sigmoid_fast(v.y) * 255.0f);
    unsigned ub = (unsigned)__float2int_rn(sigmoid_fast(v.z) * 255.0f);
    unsigned us = (unsigned)__float2int_rn(
        fminf(fmaxf(v.w, 0.0f), SIG_MAX) * (255.0f / SIG_MAX));
    return ur | (ug << 8) | (ub << 16) | (us << 24);
}

// ---- prep: [walk | hist | cvt] in one launch -------------------------------
__global__ __launch_bounds__(256) void prep(
    const float4* __restrict__ g, uint4* __restrict__ gq4,
    const float* __restrict__ origins, const float* __restrict__ dirs,
    float* __restrict__ cp, unsigned char* __restrict__ keys,
    unsigned* __restrict__ hist_part, unsigned* __restrict__ cursor,
    int B, int walk_blocks)
{
    int bid = blockIdx.x;
    if (bid < walk_blocks) {
        // -- walk: thread = ray, 3x48 bit-exact steps -> cp by RAY id -------
        int r = bid * 256 + threadIdx.x;
        if (r >= B) return;

        float oxR, oyR, ozR, dxR, dyR, dzR, ix, iy, iz, ipx, ipy, ipz;
        float tmin, tmax;
        ray_setup(origins, dirs, r, oxR, oyR, ozR, dxR, dyR, dzR,
                  ix, iy, iz, ipx, ipy, ipz, tmin, tmax);

        float t = tmin;
        #pragma unroll
        for (int s = 1; s < NSEG; ++s) {
            for (int c = 0; c < SEG_LEN / PIPE; ++c) {
                if (t >= tmax) break;
                #pragma unroll
                for (int p = 0; p < PIPE; ++p) {
                    int i0, i1, i2; float d;
                    geom_step(t, tmax, oxR, oyR, ozR, dxR, dyR, dzR,
                              ix, iy, iz, ipx, ipy, ipz, i0, i1, i2, d);
                    t = __fadd_rn(t, d);
                }
            }
            cp[(s - 1) * B + r] = t;
        }
        return;
    }

    if (bid < walk_blocks + HIST_BLOCKS) {
        // -- hist: length-estimate keys + partial histograms ----------------
        int hb = bid - walk_blocks;
        __shared__ unsigned lh[NBIN];
        lh[threadIdx.x] = 0;
        if (hb == 0) cursor[threadIdx.x] = 0;   // untouched elsewhere in prep
        __syncthreads();

        for (int r = hb * 256 + threadIdx.x; r < B; r += HIST_BLOCKS * 256) {
            float dx = dirs[3 * r], dy = dirs[3 * r + 1], dz = dirs[3 * r + 2];
            float ox = origins[3 * r], oy = origins[3 * r + 1],
                  oz = origins[3 * r + 2];
            float inv = 1.0f / sqrtf(dx * dx + dy * dy + dz * dz);
            dx *= inv; dy *= inv; dz *= inv;
            float ix = 1.0f / (dx + 1e-9f);
            float iy = 1.0f / (dy + 1e-9f);
            float iz = 1.0f / (dz + 1e-9f);
            float t1x = -ox * ix, t2x = t1x + ix;
            float t1y = -oy * iy, t2y = t1y + iy;
            float t1z = -oz * iz, t2z = t1z + iz;
            float tmin = fmaxf(fmaxf(fmaxf(fminf(t1x, t2x), fminf(t1y, t2y)),
                                     fminf(t1z, t2z)), 0.0f);
            float tmax = fminf(fminf(fmaxf(t1x, t2x), fmaxf(t1y, t2y)),
                               fmaxf(t1z, t2z));
            float sab = fabsf(dx) + fabsf(dy) + fabsf(dz);
            float est = (tmax - tmin) * 128.0f * sab / (1.0f + 0.128f * sab);
            int k = (int)fminf(fmaxf(est, 0.0f), 255.0f);
            keys[r] = (unsigned char)k;
            atomicAdd(&lh[k], 1u);
        }
        __syncthreads();
        hist_part[hb * NBIN + threadIdx.x] = lh[threadIdx.x];
        return;
    }

    // -- cvt: 4 z-voxels -> brick-ordered u8x4 ------------------------------
    int tid = (bid - walk_blocks - HIST_BLOCKS) * 256 + threadIdx.x;
    if (tid >= N_VOX / 4) return;
    int zq = tid & 31;              // z-group (4 voxels)
    int y  = (tid >> 5) & 127;
    int x  = tid >> 12;

    int src = (x * R_DIM + y) * R_DIM + 4 * zq;   // float4 index
    float4 v0 = g[src + 0];
    float4 v1 = g[src + 1];
    float4 v2 = g[src + 2];
    float4 v3 = g[src + 3];

    uint4 o;
    o.x = pack_voxel(v0);
    o.y = pack_voxel(v1);
    o.z = pack_voxel(v2);
    o.w = pack_voxel(v3);

    int bb = ((x >> 2) << 10) | ((y >> 2) << 5) | zq;
    int dst = bb * 16 + (x & 3) * 4 + (y & 3);      // uint4 index
    gq4[dst] = o;
}

// ---- scatter: build perm via per-block redundant scan + atomic cursors -----
__global__ __launch_bounds__(256) void scatter(
    const unsigned char* __restrict__ keys,
    const unsigned* __restrict__ hist_part,
    unsigned* __restrict__ cursor,
    unsigned* __restrict__ perm, int B)
{
    __shared__ unsigned h[NBIN], sc[NBIN];
    int tid = threadIdx.x;

    unsigned v = 0;
    #pragma unroll
    for (int p = 0; p < HIST_BLOCKS; ++p) v += hist_part[p * NBIN + tid];
    h[tid] = v;
    __syncthreads();
    // inclusive Hillis-Steele scan
    for (int off = 1; off < NBIN; off <<= 1) {
        unsigned y = (tid >= off) ? h[tid - off] : 0u;
        __syncthreads();
        h[tid] += y;
        __syncthreads();
    }
    sc[tid] = h[tid] - v;   // exclusive prefix
    __syncthreads();

    int r = blockIdx.x * 256 + tid;
    if (r < B) {
        int k = keys[r];
        unsigned pos = sc[k] + atomicAdd(&cursor[k], 1u);
        perm[pos] = (unsigned)r;
    }
}

// ---- render: sorted slots; 4 symmetric waves; seg s = steps [48s,48s+48) ---
__global__ __launch_bounds__(256) void volrend_seg(
    const unsigned int* __restrict__ gq,   // brick-ordered u8x4, 8.4 MB
    const float* __restrict__ cp,          // t checkpoints, 3*B floats (by rid)
    const unsigned* __restrict__ perm,     // sorted slot -> ray id
    const float* __restrict__ origins,
    const float* __restrict__ dirs,
    float* __restrict__ out,
    int B)
{
    __shared__ float4 lds[64 * (NSEG - 1)];

    int lane = threadIdx.x & 63;
    int seg  = threadIdx.x >> 6;
    int rid = (int)perm[blockIdx.x * 64 + lane];

    float oxR, oyR, ozR, dxR, dyR, dzR, ix, iy, iz, ipx, ipy, ipz, tmin, tmax;
    ray_setup(origins, dirs, rid, oxR, oyR, ozR, dxR, dyR, dzR,
              ix, iy, iz, ipx, ipy, ipz, tmin, tmax);

    float t = (seg == 0) ? tmin : cp[(seg - 1) * B + rid];

    float light = 1.0f;
    float ar = 0.0f, ag = 0.0f, ab = 0.0f;

    for (int chunk = 0; chunk < SEG_LEN / PIPE; ++chunk) {
        if (t >= tmax) break;

        unsigned int val[PIPE];
        float del[PIPE];
        float tl = t;

        #pragma unroll
        for (int p = 0; p < PIPE; ++p) {
            int i0, i1, i2; float d;
            geom_step(tl, tmax, oxR, oyR, ozR, dxR, dyR, dzR,
                      ix, iy, iz, ipx, ipy, ipz, i0, i1, i2, d);
            unsigned bb = ((unsigned)(i0 >> 2) << 10) |
                          ((unsigned)(i1 >> 2) << 5) |
                          (unsigned)(i2 >> 2);
            unsigned loc = ((unsigned)(i0 & 3) << 4) |
                           ((unsigned)(i1 & 3) << 2) |
                           (unsigned)(i2 & 3);
            val[p] = gq[(bb << 6) | loc];   // dead voxel: sigma-u8==0 -> att=1
            del[p] = d;
            tl = __fadd_rn(tl, d);
        }

        #pragma unroll
        for (int p = 0; p < PIPE; ++p) {
            unsigned int v = val[p];
            float r  = (float)(v & 255u);
            float gg = (float)((v >> 8) & 255u);
            float b  = (float)((v >> 16) & 255u);
            float sg = (float)(v >> 24);
            float att = __expf(del[p] * (-SIG_MAX / 255.0f) * sg);
            float w  = light * (1.0f - att);
            float ws = w * (1.0f / 255.0f);
            ar = fmaf(ws, r, ar);
            ag = fmaf(ws, gg, ag);
            ab = fmaf(ws, b, ab);
            light *= att;
        }

        t = tl;
    }

    // --- compose: out = A0 + L0*(A1 + L1*(A2 + L2*(A3 + L3))) --------------
    if (seg > 0) {
        lds[(seg - 1) * 64 + lane] = make_float4(ar, ag, ab, light);
    }
    __syncthreads();
    if (seg == 0) {
        float4 s1 = lds[0 * 64 + lane];
        float4 s2 = lds[1 * 64 + lane];
        float4 s3 = lds[2 * 64 + lane];
        float r3 = s3.x + s3.w, g3 = s3.y + s3.w, b3 = s3.z + s3.w;
        float r2 = fmaf(s2.w, r3, s2.x);
        float g2 = fmaf(s2.w, g3, s2.y);
        float b2 = fmaf(s2.w, b3, s2.z);
        float r1 = fmaf(s1.w, r2, s1.x);
        float g1 = fmaf(s1.w, g2, s1.y);
        float b1 = fmaf(s1.w, b2, s1.z);
        out[3 * rid + 0] = fmaf(light, r1, ar);
        out[3 * rid + 1] = fmaf(light, g1, ag);
        out[3 * rid + 2] = fmaf(light, b1, ab);
    }
}

// ---- fallback: render straight from fp32 grid (if ws too small) ------------
__global__ __launch_bounds__(256) void volrend_f32(
    const float* __restrict__ grid,
    const float* __restrict__ origins,
    const float* __restrict__ dirs,
    float* __restrict__ out,
    int B)
{
    int i = blockIdx.x * blockDim.x + threadIdx.x;
    if (i >= B) return;

    float oxR, oyR, ozR, dxR, dyR, dzR, ix, iy, iz, ipx, ipy, ipz, tmin, tmax;
    ray_setup(origins, dirs, i, oxR, oyR, ozR, dxR, dyR, dzR,
              ix, iy, iz, ipx, ipy, ipz, tmin, tmax);

    const float4* __restrict__ g4 = (const float4*)grid;

    float t = tmin;
    float light = 1.0f;
    float ar = 0.0f, ag = 0.0f, ab = 0.0f;

    for (int chunk = 0; chunk < N_STEPS / PIPE; ++chunk) {
        if (t >= tmax) break;

        float4 val[PIPE];
        float del[PIPE];
        float tl = t;

        #pragma unroll
        for (int p = 0; p < PIPE; ++p) {
            int i0, i1, i2; float d;
            geom_step(tl, tmax, oxR, oyR, ozR, dxR, dyR, dzR,
                      ix, iy, iz, ipx, ipy, ipz, i0, i1, i2, d);
            val[p] = g4[(i0 * R_DIM + i1) * R_DIM + i2];
            del[p] = d;
            tl = __fadd_rn(tl, d);
        }

        #pragma unroll
        for (int p = 0; p < PIPE; ++p) {
            float sigma = fmaxf(val[p].w, 0.0f);
            float att = __expf(-del[p] * sigma);
            float w = light * (1.0f - att);
            ar = fmaf(w, sigmoid_fast(val[p].x), ar);
            ag = fmaf(w, sigmoid_fast(val[p].y), ag);
            ab = fmaf(w, sigmoid_fast(val[p].z), ab);
            light *= att;
        }

        t = tl;
    }

    out[3 * i + 0] = ar + light;
    out[3 * i + 1] = ag + light;
    out[3 * i + 2] = ab + light;
}

extern "C" void kernel_launch(void* const* d_in, const int* in_sizes, int n_in,
                              void* d_out, int out_size, void* d_ws, size_t ws_size,
                              hipStream_t stream) {
    const float* grid    = (const float*)d_in[0];
    const float* origins = (const float*)d_in[1];
    const float* dirs    = (const float*)d_in[2];
    float* out = (float*)d_out;

    int B = in_sizes[1] / 3;

    size_t off_gq   = 0;
    size_t off_cp   = off_gq + (size_t)N_VOX * 4;
    size_t off_perm = off_cp + (size_t)(NSEG - 1) * B * 4;
    size_t off_hist = off_perm + (size_t)B * 4;
    size_t off_cur  = off_hist + (size_t)HIST_BLOCKS * NBIN * 4;
    size_t off_key  = off_cur + (size_t)NBIN * 4;
    size_t need     = off_key + (size_t)B;

    if (ws_size >= need && (B % 64) == 0) {
        char* ws = (char*)d_ws;
        uint4*         gq4  = (uint4*)(ws + off_gq);
        float*         cp   = (float*)(ws + off_cp);
        unsigned*      perm = (unsigned*)(ws + off_perm);
        unsigned*      hist = (unsigned*)(ws + off_hist);
        unsigned*      cur  = (unsigned*)(ws + off_cur);
        unsigned char* keys = (unsigned char*)(ws + off_key);

        int walk_blocks = (B + 255) / 256;
        prep<<<walk_blocks + HIST_BLOCKS + CVT_BLOCKS, 256, 0, stream>>>(
            (const float4*)grid, gq4, origins, dirs, cp, keys, hist, cur,
            B, walk_blocks);
        scatter<<<(B + 255) / 256, 256, 0, stream>>>(keys, hist, cur, perm, B);
        volrend_seg<<<B / 64, 64 * NSEG, 0, stream>>>(
            (const unsigned int*)gq4, cp, perm, origins, dirs, out, B);
    } else {
        volrend_f32<<<(B + 255) / 256, 256, 0, stream>>>(grid, origins, dirs,
                                                         out, B);
    }
}

// Round 9
// 124.075 us; speedup vs baseline: 1.3959x; 1.3959x over previous
//
#include <hip/hip_runtime.h>

// VolumeRenderer R19: R18 with a contention-free scatter.
// R18 counters: scatter = 57us, VALUBusy 0.19% => pure atomic serialization
// (65536 device atomics-with-return onto 256 counters in 16 cache lines;
// clustered ray-length keys make hot bins thousands deep). The sort theory
// (seg wave-max divergence, ~2.5x wasted steps) was never actually tested.
// R19 scatter v2:
//   1) block-local LDS histogram (LDS atomics),
//   2) ONE global atomic per (block, nonempty bin) onto a 64B-PADDED cursor
//      (cursor[k*16]) -> same-address depth <=256, no line sharing,
//   3) block-local ranks via LDS atomics (stability irrelevant: any
//      within-bin order is a valid permutation; rays write their own out).
// Everything else byte-identical to R18 for a clean A/B on seg.

constexpr int   R_DIM    = 128;
constexpr int   N_VOX    = R_DIM * R_DIM * R_DIM;
constexpr int   N_STEPS  = 192;
constexpr int   NSEG     = 4;
constexpr int   SEG_LEN  = N_STEPS / NSEG;   // 48
constexpr float STEP_SZ  = 0.001f;
constexpr float CUBE_SZ  = 1.0f / 128.0f;
constexpr int   PIPE     = 8;
constexpr float SIG_MAX  = 5.5f;
constexpr int   CVT_BLOCKS  = (N_VOX / 4 + 255) / 256;   // 2048
constexpr int   HIST_BLOCKS = 32;
constexpr int   NBIN        = 256;
constexpr int   CUR_STRIDE  = 16;            // 64B padding per bin

__device__ __forceinline__ float sigmoid_fast(float x) {
    return __builtin_amdgcn_rcpf(1.0f + __expf(-x));
}

// One geometric DDA step -> cell coords + exact delta. Bit-identical to the
// reference walk. smin==0 exactly (f in [0,1] -> every per-axis lo <= 0).
__device__ __forceinline__ void geom_step(
    float tl, float tmax,
    float oxR, float oyR, float ozR, float dxR, float dyR, float dzR,
    float ix, float iy, float iz, float ipx, float ipy, float ipz,
    int& i0, int& i1, int& i2, float& d)
{
    float px = __fadd_rn(oxR, __fmul_rn(tl, dxR));
    float py = __fadd_rn(oyR, __fmul_rn(tl, dyR));
    float pz = __fadd_rn(ozR, __fmul_rn(tl, dzR));

    float c0 = fminf(fmaxf(floorf(px), 0.0f), 127.0f);
    float c1 = fminf(fmaxf(floorf(py), 0.0f), 127.0f);
    float c2 = fminf(fmaxf(floorf(pz), 0.0f), 127.0f);
    i0 = (int)c0;   // dead (DCE'd) in walk-only use
    i1 = (int)c1;
    i2 = (int)c2;

    float t1x = __fmul_rn(__fsub_rn(c0, px), ix);
    float t1y = __fmul_rn(__fsub_rn(c1, py), iy);
    float t1z = __fmul_rn(__fsub_rn(c2, pz), iz);
    float hix = __fadd_rn(t1x, ipx);
    float hiy = __fadd_rn(t1y, ipy);
    float hiz = __fadd_rn(t1z, ipz);
    float smax = fminf(fminf(fminf(hix, hiy), hiz), 1e9f);

    d = __fadd_rn(__fmul_rn(smax, CUBE_SZ), STEP_SZ);
    d = (tl < tmax) ? d : 0.0f;   // inactive -> exact no-op (t frozen)
}

__device__ __forceinline__ void ray_setup(
    const float* __restrict__ origins, const float* __restrict__ dirs, int i,
    float& oxR, float& oyR, float& ozR, float& dxR, float& dyR, float& dzR,
    float& ix, float& iy, float& iz,
    float& ipx, float& ipy, float& ipz,
    float& tmin, float& tmax)
{
    float ox = origins[3 * i + 0];
    float oy = origins[3 * i + 1];
    float oz = origins[3 * i + 2];
    float dx = dirs[3 * i + 0];
    float dy = dirs[3 * i + 1];
    float dz = dirs[3 * i + 2];

    float n2 = __fadd_rn(__fadd_rn(__fmul_rn(dx, dx), __fmul_rn(dy, dy)),
                         __fmul_rn(dz, dz));
    float nrm = sqrtf(n2);
    dx = dx / nrm;
    dy = dy / nrm;
    dz = dz / nrm;

    ix = 1.0f / __fadd_rn(dx, 1e-9f);
    iy = 1.0f / __fadd_rn(dy, 1e-9f);
    iz = 1.0f / __fadd_rn(dz, 1e-9f);

    ipx = fmaxf(ix, 0.0f);
    ipy = fmaxf(iy, 0.0f);
    ipz = fmaxf(iz, 0.0f);

    float t1x = __fmul_rn(-ox, ix), t2x = __fadd_rn(t1x, ix);
    float t1y = __fmul_rn(-oy, iy), t2y = __fadd_rn(t1y, iy);
    float t1z = __fmul_rn(-oz, iz), t2z = __fadd_rn(t1z, iz);
    float lox = fminf(t1x, t2x), hix = fmaxf(t1x, t2x);
    float loy = fminf(t1y, t2y), hiy = fmaxf(t1y, t2y);
    float loz = fminf(t1z, t2z), hiz = fmaxf(t1z, t2z);
    tmin = fmaxf(fmaxf(fmaxf(lox, loy), loz), 0.0f);
    tmax = fminf(fminf(fminf(hix, hiy), hiz), 1e9f);

    // exact *2^7 (scaling lemma keeps the walk bit-identical)
    oxR = __fmul_rn(ox, 128.0f);
    oyR = __fmul_rn(oy, 128.0f);
    ozR = __fmul_rn(oz, 128.0f);
    dxR = __fmul_rn(dx, 128.0f);
    dyR = __fmul_rn(dy, 128.0f);
    dzR = __fmul_rn(dz, 128.0f);
}

__device__ __forceinline__ unsigned pack_voxel(float4 v) {
    unsigned ur = (unsigned)__float2int_rn(sigmoid_fast(v.x) * 255.0f);
    unsigned ug = (unsigned)__float2int_rn(sigmoid_fast(v.y) * 255.0f);
    unsigned ub = (unsigned)__float2int_rn(sigmoid_fast(v.z) * 255.0f);
    unsigned us = (unsigned)__float2int_rn(
        fminf(fmaxf(v.w, 0.0f), SIG_MAX) * (255.0f / SIG_MAX));
    return ur | (ug << 8) | (ub << 16) | (us << 24);
}

// ---- prep: [walk | hist | cvt] in one launch -------------------------------
__global__ __launch_bounds__(256) void prep(
    const float4* __restrict__ g, uint4* __restrict__ gq4,
    const float* __restrict__ origins, const float* __restrict__ dirs,
    float* __restrict__ cp, unsigned char* __restrict__ keys,
    unsigned* __restrict__ hist_part, unsigned* __restrict__ cursor,
    int B, int walk_blocks)
{
    int bid = blockIdx.x;
    if (bid < walk_blocks) {
        // -- walk: thread = ray, 3x48 bit-exact steps -> cp by RAY id -------
        int r = bid * 256 + threadIdx.x;
        if (r >= B) return;

        float oxR, oyR, ozR, dxR, dyR, dzR, ix, iy, iz, ipx, ipy, ipz;
        float tmin, tmax;
        ray_setup(origins, dirs, r, oxR, oyR, ozR, dxR, dyR, dzR,
                  ix, iy, iz, ipx, ipy, ipz, tmin, tmax);

        float t = tmin;
        #pragma unroll
        for (int s = 1; s < NSEG; ++s) {
            for (int c = 0; c < SEG_LEN / PIPE; ++c) {
                if (t >= tmax) break;
                #pragma unroll
                for (int p = 0; p < PIPE; ++p) {
                    int i0, i1, i2; float d;
                    geom_step(t, tmax, oxR, oyR, ozR, dxR, dyR, dzR,
                              ix, iy, iz, ipx, ipy, ipz, i0, i1, i2, d);
                    t = __fadd_rn(t, d);
                }
            }
            cp[(s - 1) * B + r] = t;
        }
        return;
    }

    if (bid < walk_blocks + HIST_BLOCKS) {
        // -- hist: length-estimate keys + partial histograms ----------------
        int hb = bid - walk_blocks;
        __shared__ unsigned lh[NBIN];
        lh[threadIdx.x] = 0;
        if (hb == 0) cursor[threadIdx.x * CUR_STRIDE] = 0;
        __syncthreads();

        for (int r = hb * 256 + threadIdx.x; r < B; r += HIST_BLOCKS * 256) {
            float dx = dirs[3 * r], dy = dirs[3 * r + 1], dz = dirs[3 * r + 2];
            float ox = origins[3 * r], oy = origins[3 * r + 1],
                  oz = origins[3 * r + 2];
            float inv = 1.0f / sqrtf(dx * dx + dy * dy + dz * dz);
            dx *= inv; dy *= inv; dz *= inv;
            float ix = 1.0f / (dx + 1e-9f);
            float iy = 1.0f / (dy + 1e-9f);
            float iz = 1.0f / (dz + 1e-9f);
            float t1x = -ox * ix, t2x = t1x + ix;
            float t1y = -oy * iy, t2y = t1y + iy;
            float t1z = -oz * iz, t2z = t1z + iz;
            float tmin = fmaxf(fmaxf(fmaxf(fminf(t1x, t2x), fminf(t1y, t2y)),
                                     fminf(t1z, t2z)), 0.0f);
            float tmax = fminf(fminf(fmaxf(t1x, t2x), fmaxf(t1y, t2y)),
                               fmaxf(t1z, t2z));
            float sab = fabsf(dx) + fabsf(dy) + fabsf(dz);
            float est = (tmax - tmin) * 128.0f * sab / (1.0f + 0.128f * sab);
            int k = (int)fminf(fmaxf(est, 0.0f), 255.0f);
            keys[r] = (unsigned char)k;
            atomicAdd(&lh[k], 1u);
        }
        __syncthreads();
        hist_part[hb * NBIN + threadIdx.x] = lh[threadIdx.x];
        return;
    }

    // -- cvt: 4 z-voxels -> brick-ordered u8x4 ------------------------------
    int tid = (bid - walk_blocks - HIST_BLOCKS) * 256 + threadIdx.x;
    if (tid >= N_VOX / 4) return;
    int zq = tid & 31;              // z-group (4 voxels)
    int y  = (tid >> 5) & 127;
    int x  = tid >> 12;

    int src = (x * R_DIM + y) * R_DIM + 4 * zq;   // float4 index
    float4 v0 = g[src + 0];
    float4 v1 = g[src + 1];
    float4 v2 = g[src + 2];
    float4 v3 = g[src + 3];

    uint4 o;
    o.x = pack_voxel(v0);
    o.y = pack_voxel(v1);
    o.z = pack_voxel(v2);
    o.w = pack_voxel(v3);

    int bb = ((x >> 2) << 10) | ((y >> 2) << 5) | zq;
    int dst = bb * 16 + (x & 3) * 4 + (y & 3);      // uint4 index
    gq4[dst] = o;
}

// ---- scatter v2: LDS-aggregated, padded global cursors ---------------------
__global__ __launch_bounds__(256) void scatter(
    const unsigned char* __restrict__ keys,
    const unsigned* __restrict__ hist_part,
    unsigned* __restrict__ cursor,         // bin k at [k*CUR_STRIDE]
    unsigned* __restrict__ perm, int B)
{
    __shared__ unsigned h[NBIN], sc[NBIN], lh[NBIN], lbase[NBIN];
    int tid = threadIdx.x;

    // global hist + exclusive scan (cheap: 32KB L2 reads per block)
    unsigned v = 0;
    #pragma unroll
    for (int p = 0; p < HIST_BLOCKS; ++p) v += hist_part[p * NBIN + tid];
    h[tid] = v;
    lh[tid] = 0;
    __syncthreads();
    for (int off = 1; off < NBIN; off <<= 1) {
        unsigned y = (tid >= off) ? h[tid - off] : 0u;
        __syncthreads();
        h[tid] += y;
        __syncthreads();
    }
    sc[tid] = h[tid] - v;   // global exclusive bin start
    __syncthreads();

    // block-local histogram (LDS atomics)
    int r = blockIdx.x * 256 + tid;
    int k = 0;
    bool live = (r < B);
    if (live) {
        k = keys[r];
        atomicAdd(&lh[k], 1u);
    }
    __syncthreads();

    // one padded global atomic per nonempty bin -> block base in bin
    unsigned cnt = lh[tid];
    if (cnt) lbase[tid] = sc[tid] + atomicAdd(&cursor[tid * CUR_STRIDE], cnt);
    __syncthreads();

    // block-local ranks (LDS atomics; within-bin order arbitrary = fine)
    h[tid] = 0;
    __syncthreads();
    if (live) {
        unsigned rk = atomicAdd(&h[k], 1u);
        perm[lbase[k] + rk] = (unsigned)r;
    }
}

// ---- render: sorted slots; 4 symmetric waves; seg s = steps [48s,48s+48) ---
__global__ __launch_bounds__(256) void volrend_seg(
    const unsigned int* __restrict__ gq,   // brick-ordered u8x4, 8.4 MB
    const float* __restrict__ cp,          // t checkpoints, 3*B floats (by rid)
    const unsigned* __restrict__ perm,     // sorted slot -> ray id
    const float* __restrict__ origins,
    const float* __restrict__ dirs,
    float* __restrict__ out,
    int B)
{
    __shared__ float4 lds[64 * (NSEG - 1)];

    int lane = threadIdx.x & 63;
    int seg  = threadIdx.x >> 6;
    int rid = (int)perm[blockIdx.x * 64 + lane];

    float oxR, oyR, ozR, dxR, dyR, dzR, ix, iy, iz, ipx, ipy, ipz, tmin, tmax;
    ray_setup(origins, dirs, rid, oxR, oyR, ozR, dxR, dyR, dzR,
              ix, iy, iz, ipx, ipy, ipz, tmin, tmax);

    float t = (seg == 0) ? tmin : cp[(seg - 1) * B + rid];

    float light = 1.0f;
    float ar = 0.0f, ag = 0.0f, ab = 0.0f;

    for (int chunk = 0; chunk < SEG_LEN / PIPE; ++chunk) {
        if (t >= tmax) break;

        unsigned int val[PIPE];
        float del[PIPE];
        float tl = t;

        #pragma unroll
        for (int p = 0; p < PIPE; ++p) {
            int i0, i1, i2; float d;
            geom_step(tl, tmax, oxR, oyR, ozR, dxR, dyR, dzR,
                      ix, iy, iz, ipx, ipy, ipz, i0, i1, i2, d);
            unsigned bb = ((unsigned)(i0 >> 2) << 10) |
                          ((unsigned)(i1 >> 2) << 5) |
                          (unsigned)(i2 >> 2);
            unsigned loc = ((unsigned)(i0 & 3) << 4) |
                           ((unsigned)(i1 & 3) << 2) |
                           (unsigned)(i2 & 3);
            val[p] = gq[(bb << 6) | loc];   // dead voxel: sigma-u8==0 -> att=1
            del[p] = d;
            tl = __fadd_rn(tl, d);
        }

        #pragma unroll
        for (int p = 0; p < PIPE; ++p) {
            unsigned int v = val[p];
            float r  = (float)(v & 255u);
            float gg = (float)((v >> 8) & 255u);
            float b  = (float)((v >> 16) & 255u);
            float sg = (float)(v >> 24);
            float att = __expf(del[p] * (-SIG_MAX / 255.0f) * sg);
            float w  = light * (1.0f - att);
            float ws = w * (1.0f / 255.0f);
            ar = fmaf(ws, r, ar);
            ag = fmaf(ws, gg, ag);
            ab = fmaf(ws, b, ab);
            light *= att;
        }

        t = tl;
    }

    // --- compose: out = A0 + L0*(A1 + L1*(A2 + L2*(A3 + L3))) --------------
    if (seg > 0) {
        lds[(seg - 1) * 64 + lane] = make_float4(ar, ag, ab, light);
    }
    __syncthreads();
    if (seg == 0) {
        float4 s1 = lds[0 * 64 + lane];
        float4 s2 = lds[1 * 64 + lane];
        float4 s3 = lds[2 * 64 + lane];
        float r3 = s3.x + s3.w, g3 = s3.y + s3.w, b3 = s3.z + s3.w;
        float r2 = fmaf(s2.w, r3, s2.x);
        float g2 = fmaf(s2.w, g3, s2.y);
        float b2 = fmaf(s2.w, b3, s2.z);
        float r1 = fmaf(s1.w, r2, s1.x);
        float g1 = fmaf(s1.w, g2, s1.y);
        float b1 = fmaf(s1.w, b2, s1.z);
        out[3 * rid + 0] = fmaf(light, r1, ar);
        out[3 * rid + 1] = fmaf(light, g1, ag);
        out[3 * rid + 2] = fmaf(light, b1, ab);
    }
}

// ---- fallback: render straight from fp32 grid (if ws too small) ------------
__global__ __launch_bounds__(256) void volrend_f32(
    const float* __restrict__ grid,
    const float* __restrict__ origins,
    const float* __restrict__ dirs,
    float* __restrict__ out,
    int B)
{
    int i = blockIdx.x * blockDim.x + threadIdx.x;
    if (i >= B) return;

    float oxR, oyR, ozR, dxR, dyR, dzR, ix, iy, iz, ipx, ipy, ipz, tmin, tmax;
    ray_setup(origins, dirs, i, oxR, oyR, ozR, dxR, dyR, dzR,
              ix, iy, iz, ipx, ipy, ipz, tmin, tmax);

    const float4* __restrict__ g4 = (const float4*)grid;

    float t = tmin;
    float light = 1.0f;
    float ar = 0.0f, ag = 0.0f, ab = 0.0f;

    for (int chunk = 0; chunk < N_STEPS / PIPE; ++chunk) {
        if (t >= tmax) break;

        float4 val[PIPE];
        float del[PIPE];
        float tl = t;

        #pragma unroll
        for (int p = 0; p < PIPE; ++p) {
            int i0, i1, i2; float d;
            geom_step(tl, tmax, oxR, oyR, ozR, dxR, dyR, dzR,
                      ix, iy, iz, ipx, ipy, ipz, i0, i1, i2, d);
            val[p] = g4[(i0 * R_DIM + i1) * R_DIM + i2];
            del[p] = d;
            tl = __fadd_rn(tl, d);
        }

        #pragma unroll
        for (int p = 0; p < PIPE; ++p) {
            float sigma = fmaxf(val[p].w, 0.0f);
            float att = __expf(-del[p] * sigma);
            float w = light * (1.0f - att);
            ar = fmaf(w, sigmoid_fast(val[p].x), ar);
            ag = fmaf(w, sigmoid_fast(val[p].y), ag);
            ab = fmaf(w, sigmoid_fast(val[p].z), ab);
            light *= att;
        }

        t = tl;
    }

    out[3 * i + 0] = ar + light;
    out[3 * i + 1] = ag + light;
    out[3 * i + 2] = ab + light;
}

extern "C" void kernel_launch(void* const* d_in, const int* in_sizes, int n_in,
                              void* d_out, int out_size, void* d_ws, size_t ws_size,
                              hipStream_t stream) {
    const float* grid    = (const float*)d_in[0];
    const float* origins = (const float*)d_in[1];
    const float* dirs    = (const float*)d_in[2];
    float* out = (float*)d_out;

    int B = in_sizes[1] / 3;

    size_t off_gq   = 0;
    size_t off_cp   = off_gq + (size_t)N_VOX * 4;
    size_t off_perm = off_cp + (size_t)(NSEG - 1) * B * 4;
    size_t off_hist = off_perm + (size_t)B * 4;
    size_t off_cur  = off_hist + (size_t)HIST_BLOCKS * NBIN * 4;
    size_t off_key  = off_cur + (size_t)NBIN * CUR_STRIDE * 4;
    size_t need     = off_key + (size_t)B;

    if (ws_size >= need && (B % 64) == 0) {
        char* ws = (char*)d_ws;
        uint4*         gq4  = (uint4*)(ws + off_gq);
        float*         cp   = (float*)(ws + off_cp);
        unsigned*      perm = (unsigned*)(ws + off_perm);
        unsigned*      hist = (unsigned*)(ws + off_hist);
        unsigned*      cur  = (unsigned*)(ws + off_cur);
        unsigned char* keys = (unsigned char*)(ws + off_key);

        int walk_blocks = (B + 255) / 256;
        prep<<<walk_blocks + HIST_BLOCKS + CVT_BLOCKS, 256, 0, stream>>>(
            (const float4*)grid, gq4, origins, dirs, cp, keys, hist, cur,
            B, walk_blocks);
        scatter<<<(B + 255) / 256, 256, 0, stream>>>(keys, hist, cur, perm, B);
        volrend_seg<<<B / 64, 64 * NSEG, 0, stream>>>(
            (const unsigned int*)gq4, cp, perm, origins, dirs, out, B);
    } else {
        volrend_f32<<<(B + 255) / 256, 256, 0, stream>>>(grid, origins, dirs,
                                                         out, B);
    }
}

// Round 11
// 107.453 us; speedup vs baseline: 1.6119x; 1.1547x over previous
//
#include <hip/hip_runtime.h>

// VolumeRenderer R20 = R12 restore (best verified: 108.0 µs).
// R13–R19 systematically tested every structural lever on the render
// kernel's ~30µs: prewalk removal (null), 8 waves/SIMD (worse), lane=step
// scan (kernel fast, pipeline worse), 3-step segments (worse), ray sort
// by length (worse even with contention-free scatter). Conclusion: seg is
// chain-latency/gather-stall bound at 4 waves/SIMD, insensitive to executed
// step count; the sort overhead never repaid. Decomposition vs floors:
//   fill 46 (harness) + cvt ~23 (134MB HBM read, floor 21) + seg ~31 +
//   gaps ~8  => R12's 108 is within a few µs of this structure's floor.
// This file is byte-equivalent in behavior to the R12 submission.

constexpr int   R_DIM    = 128;
constexpr int   N_VOX    = R_DIM * R_DIM * R_DIM;
constexpr int   N_STEPS  = 192;
constexpr int   NSEG     = 4;
constexpr int   SEG_LEN  = N_STEPS / NSEG;   // 48
constexpr float STEP_SZ  = 0.001f;
constexpr float CUBE_SZ  = 1.0f / 128.0f;
constexpr int   PIPE     = 8;
constexpr float SIG_MAX  = 5.5f;

__device__ __forceinline__ float sigmoid_fast(float x) {
    return __builtin_amdgcn_rcpf(1.0f + __expf(-x));
}

// One geometric DDA step -> cell coords + exact delta. Bit-identical to the
// reference walk. smin==0 exactly (f in [0,1] -> every per-axis lo <= 0).
__device__ __forceinline__ void geom_step(
    float tl, float tmax,
    float oxR, float oyR, float ozR, float dxR, float dyR, float dzR,
    float ix, float iy, float iz, float ipx, float ipy, float ipz,
    int& i0, int& i1, int& i2, float& d)
{
    float px = __fadd_rn(oxR, __fmul_rn(tl, dxR));
    float py = __fadd_rn(oyR, __fmul_rn(tl, dyR));
    float pz = __fadd_rn(ozR, __fmul_rn(tl, dzR));

    // float-domain clamp: med3(floor(p), 0, 127); same value as int clamp
    float c0 = fminf(fmaxf(floorf(px), 0.0f), 127.0f);
    float c1 = fminf(fmaxf(floorf(py), 0.0f), 127.0f);
    float c2 = fminf(fmaxf(floorf(pz), 0.0f), 127.0f);
    i0 = (int)c0;   // dead (DCE'd) in prewalk
    i1 = (int)c1;
    i2 = (int)c2;

    // t1 = rn((-f)*i) via (c-p) = -f exactly; hi = rn(t1 + max(i,0))
    float t1x = __fmul_rn(__fsub_rn(c0, px), ix);
    float t1y = __fmul_rn(__fsub_rn(c1, py), iy);
    float t1z = __fmul_rn(__fsub_rn(c2, pz), iz);
    float hix = __fadd_rn(t1x, ipx);
    float hiy = __fadd_rn(t1y, ipy);
    float hiz = __fadd_rn(t1z, ipz);
    float smax = fminf(fminf(fminf(hix, hiy), hiz), 1e9f);

    d = __fadd_rn(__fmul_rn(smax, CUBE_SZ), STEP_SZ);
    d = (tl < tmax) ? d : 0.0f;   // inactive -> exact no-op (t frozen)
}

__device__ __forceinline__ void ray_setup(
    const float* __restrict__ origins, const float* __restrict__ dirs, int i,
    float& oxR, float& oyR, float& ozR, float& dxR, float& dyR, float& dzR,
    float& ix, float& iy, float& iz,
    float& ipx, float& ipy, float& ipz,
    float& tmin, float& tmax)
{
    float ox = origins[3 * i + 0];
    float oy = origins[3 * i + 1];
    float oz = origins[3 * i + 2];
    float dx = dirs[3 * i + 0];
    float dy = dirs[3 * i + 1];
    float dz = dirs[3 * i + 2];

    float n2 = __fadd_rn(__fadd_rn(__fmul_rn(dx, dx), __fmul_rn(dy, dy)),
                         __fmul_rn(dz, dz));
    float nrm = sqrtf(n2);
    dx = dx / nrm;
    dy = dy / nrm;
    dz = dz / nrm;

    ix = 1.0f / __fadd_rn(dx, 1e-9f);
    iy = 1.0f / __fadd_rn(dy, 1e-9f);
    iz = 1.0f / __fadd_rn(dz, 1e-9f);

    ipx = fmaxf(ix, 0.0f);
    ipy = fmaxf(iy, 0.0f);
    ipz = fmaxf(iz, 0.0f);

    float t1x = __fmul_rn(-ox, ix), t2x = __fadd_rn(t1x, ix);
    float t1y = __fmul_rn(-oy, iy), t2y = __fadd_rn(t1y, iy);
    float t1z = __fmul_rn(-oz, iz), t2z = __fadd_rn(t1z, iz);
    float lox = fminf(t1x, t2x), hix = fmaxf(t1x, t2x);
    float loy = fminf(t1y, t2y), hiy = fmaxf(t1y, t2y);
    float loz = fminf(t1z, t2z), hiz = fmaxf(t1z, t2z);
    tmin = fmaxf(fmaxf(fmaxf(lox, loy), loz), 0.0f);
    tmax = fminf(fminf(fminf(hix, hiy), hiz), 1e9f);

    // exact *2^7 (scaling lemma keeps the walk bit-identical)
    oxR = __fmul_rn(ox, 128.0f);
    oyR = __fmul_rn(oy, 128.0f);
    ozR = __fmul_rn(oz, 128.0f);
    dxR = __fmul_rn(dx, 128.0f);
    dyR = __fmul_rn(dy, 128.0f);
    dzR = __fmul_rn(dz, 128.0f);
}

// ---- pre-pass: fp32 grid -> brick-ordered u8x4 voxels ----------------------
__device__ __forceinline__ unsigned pack_voxel(float4 v) {
    unsigned ur = (unsigned)__float2int_rn(sigmoid_fast(v.x) * 255.0f);
    unsigned ug = (unsigned)__float2int_rn(sigmoid_fast(v.y) * 255.0f);
    unsigned ub = (unsigned)__float2int_rn(sigmoid_fast(v.z) * 255.0f);
    unsigned us = (unsigned)__float2int_rn(
        fminf(fmaxf(v.w, 0.0f), SIG_MAX) * (255.0f / SIG_MAX));
    return ur | (ug << 8) | (ub << 16) | (us << 24);
}

__global__ __launch_bounds__(256) void cvt_brick(
    const float4* __restrict__ g, uint4* __restrict__ gq4)
{
    int tid = blockIdx.x * blockDim.x + threadIdx.x;
    if (tid >= N_VOX / 4) return;
    int zq = tid & 31;              // z-group (4 voxels)
    int y  = (tid >> 5) & 127;
    int x  = tid >> 12;

    int src = (x * R_DIM + y) * R_DIM + 4 * zq;   // float4 index
    float4 v0 = g[src + 0];
    float4 v1 = g[src + 1];
    float4 v2 = g[src + 2];
    float4 v3 = g[src + 3];

    uint4 o;
    o.x = pack_voxel(v0);
    o.y = pack_voxel(v1);
    o.z = pack_voxel(v2);
    o.w = pack_voxel(v3);

    // brick-ordered destination: bid = bx<<10|by<<5|bz, loc = lx<<4|ly<<2|lz
    int bid = ((x >> 2) << 10) | ((y >> 2) << 5) | zq;
    int dst = bid * 16 + (x & 3) * 4 + (y & 3);     // uint4 index
    gq4[dst] = o;
}

// ---- render: 4 waves/block; wave s renders steps [s*48, s*48+48) -----------
__global__ __launch_bounds__(256) void volrend_seg(
    const unsigned int* __restrict__ gq,   // brick-ordered u8x4, 8.4 MB
    const float* __restrict__ origins,
    const float* __restrict__ dirs,
    float* __restrict__ out,
    int B)
{
    __shared__ float4 lds[64 * (NSEG - 1)];

    int lane = threadIdx.x & 63;
    int seg  = threadIdx.x >> 6;
    int i = blockIdx.x * 64 + lane;

    float oxR, oyR, ozR, dxR, dyR, dzR, ix, iy, iz, ipx, ipy, ipz, tmin, tmax;
    ray_setup(origins, dirs, i, oxR, oyR, ozR, dxR, dyR, dzR,
              ix, iy, iz, ipx, ipy, ipz, tmin, tmax);

    float t = tmin;

    // --- prewalk: seg*48 geometry-only steps (bit-exact, no loads) ---------
    int pre_chunks = seg * (SEG_LEN / PIPE);
    for (int c = 0; c < pre_chunks; ++c) {
        if (t >= tmax) break;
        #pragma unroll
        for (int p = 0; p < PIPE; ++p) {
            int i0, i1, i2; float d;
            geom_step(t, tmax, oxR, oyR, ozR, dxR, dyR, dzR,
                      ix, iy, iz, ipx, ipy, ipz, i0, i1, i2, d);
            t = __fadd_rn(t, d);
        }
    }

    // --- render 48 steps with local transmittance --------------------------
    float light = 1.0f;
    float ar = 0.0f, ag = 0.0f, ab = 0.0f;

    for (int chunk = 0; chunk < SEG_LEN / PIPE; ++chunk) {
        if (t >= tmax) break;

        unsigned int val[PIPE];
        float del[PIPE];
        float tl = t;

        #pragma unroll
        for (int p = 0; p < PIPE; ++p) {
            int i0, i1, i2; float d;
            geom_step(tl, tmax, oxR, oyR, ozR, dxR, dyR, dzR,
                      ix, iy, iz, ipx, ipy, ipz, i0, i1, i2, d);
            unsigned bid = ((unsigned)(i0 >> 2) << 10) |
                           ((unsigned)(i1 >> 2) << 5) |
                           (unsigned)(i2 >> 2);
            unsigned loc = ((unsigned)(i0 & 3) << 4) |
                           ((unsigned)(i1 & 3) << 2) |
                           (unsigned)(i2 & 3);
            val[p] = gq[(bid << 6) | loc];   // dead voxel: sigma-u8==0 -> att=1
            del[p] = d;
            tl = __fadd_rn(tl, d);
        }

        #pragma unroll
        for (int p = 0; p < PIPE; ++p) {
            unsigned int v = val[p];
            // byte-extract casts compile to v_cvt_f32_ubyte0..3
            float r  = (float)(v & 255u);
            float gg = (float)((v >> 8) & 255u);
            float b  = (float)((v >> 16) & 255u);
            float sg = (float)(v >> 24);
            float att = __expf(del[p] * (-SIG_MAX / 255.0f) * sg);
            float w  = light * (1.0f - att);
            float ws = w * (1.0f / 255.0f);
            ar = fmaf(ws, r, ar);
            ag = fmaf(ws, gg, ag);
            ab = fmaf(ws, b, ab);
            light *= att;
        }

        t = tl;
    }

    // --- compose: out = A0 + L0*(A1 + L1*(A2 + L2*(A3 + L3))) --------------
    if (seg > 0) {
        lds[(seg - 1) * 64 + lane] = make_float4(ar, ag, ab, light);
    }
    __syncthreads();
    if (seg == 0) {
        float4 s1 = lds[0 * 64 + lane];
        float4 s2 = lds[1 * 64 + lane];
        float4 s3 = lds[2 * 64 + lane];
        float r3 = s3.x + s3.w, g3 = s3.y + s3.w, b3 = s3.z + s3.w;
        float r2 = fmaf(s2.w, r3, s2.x);
        float g2 = fmaf(s2.w, g3, s2.y);
        float b2 = fmaf(s2.w, b3, s2.z);
        float r1 = fmaf(s1.w, r2, s1.x);
        float g1 = fmaf(s1.w, g2, s1.y);
        float b1 = fmaf(s1.w, b2, s1.z);
        out[3 * i + 0] = fmaf(light, r1, ar);
        out[3 * i + 1] = fmaf(light, g1, ag);
        out[3 * i + 2] = fmaf(light, b1, ab);
    }
}

// ---- fallback: render straight from fp32 grid (if ws too small) ------------
__global__ __launch_bounds__(256) void volrend_f32(
    const float* __restrict__ grid,
    const float* __restrict__ origins,
    const float* __restrict__ dirs,
    float* __restrict__ out,
    int B)
{
    int i = blockIdx.x * blockDim.x + threadIdx.x;
    if (i >= B) return;

    float oxR, oyR, ozR, dxR, dyR, dzR, ix, iy, iz, ipx, ipy, ipz, tmin, tmax;
    ray_setup(origins, dirs, i, oxR, oyR, ozR, dxR, dyR, dzR,
              ix, iy, iz, ipx, ipy, ipz, tmin, tmax);

    const float4* __restrict__ g4 = (const float4*)grid;

    float t = tmin;
    float light = 1.0f;
    float ar = 0.0f, ag = 0.0f, ab = 0.0f;

    for (int chunk = 0; chunk < N_STEPS / PIPE; ++chunk) {
        if (t >= tmax) break;

        float4 val[PIPE];
        float del[PIPE];
        float tl = t;

        #pragma unroll
        for (int p = 0; p < PIPE; ++p) {
            int i0, i1, i2; float d;
            geom_step(tl, tmax, oxR, oyR, ozR, dxR, dyR, dzR,
                      ix, iy, iz, ipx, ipy, ipz, i0, i1, i2, d);
            val[p] = g4[(i0 * R_DIM + i1) * R_DIM + i2];
            del[p] = d;
            tl = __fadd_rn(tl, d);
        }

        #pragma unroll
        for (int p = 0; p < PIPE; ++p) {
            float sigma = fmaxf(val[p].w, 0.0f);
            float att = __expf(-del[p] * sigma);
            float w = light * (1.0f - att);
            ar = fmaf(w, sigmoid_fast(val[p].x), ar);
            ag = fmaf(w, sigmoid_fast(val[p].y), ag);
            ab = fmaf(w, sigmoid_fast(val[p].z), ab);
            light *= att;
        }

        t = tl;
    }

    out[3 * i + 0] = ar + light;
    out[3 * i + 1] = ag + light;
    out[3 * i + 2] = ab + light;
}

extern "C" void kernel_launch(void* const* d_in, const int* in_sizes, int n_in,
                              void* d_out, int out_size, void* d_ws, size_t ws_size,
                              hipStream_t stream) {
    const float* grid    = (const float*)d_in[0];
    const float* origins = (const float*)d_in[1];
    const float* dirs    = (const float*)d_in[2];
    float* out = (float*)d_out;

    int B = in_sizes[1] / 3;

    size_t need = (size_t)N_VOX * 4;   // brick-ordered u8x4 voxels, 8.4 MB
    if (ws_size >= need && (B % 64) == 0) {
        uint4* gq4 = (uint4*)d_ws;
        cvt_brick<<<(N_VOX / 4 + 255) / 256, 256, 0, stream>>>(
            (const float4*)grid, gq4);
        volrend_seg<<<B / 64, 64 * NSEG, 0, stream>>>(
            (const unsigned int*)gq4, origins, dirs, out, B);
    } else {
        volrend_f32<<<(B + 255) / 256, 256, 0, stream>>>(grid, origins, dirs,
                                                         out, B);
    }
}